// Round 1
// baseline (548.033 us; speedup 1.0000x reference)
//
#include <hip/hip_runtime.h>
#include <hip/hip_cooperative_groups.h>
#include <math.h>

namespace cg = cooperative_groups;

#define BB 16
#define MM 2048
#define SS 6
#define EE 128
#define LCC 512
#define VV 32000

typedef __attribute__((ext_vector_type(8))) __bf16 bf16x8;
typedef __attribute__((ext_vector_type(4))) float f32x4;

#define XS_STRIDE 264   // 256+8 bf16 pad
#define HS_STRIDE 136   // 128+8 bf16 pad

static __device__ inline unsigned short bfbits(float x) {
    __bf16 h = (__bf16)x;
    return __builtin_bit_cast(unsigned short, h);
}

// ---------------------------------------------------------------------------
// prep_small: W1/W2 fp32 -> bf16 transposed [n][k]; uqA = uqB = 0.
// ---------------------------------------------------------------------------
#define N_W1  (256 * 128)              // 32,768
#define N_W2  (128 * 128)              // 16,384
#define N_UQ  (BB * EE)                // 2,048
#define N_PREP (N_W1 + N_W2 + 2 * N_UQ)   // 53,248 = 208*256

__global__ __launch_bounds__(256)
void prep_small(const float* __restrict__ W1, const float* __restrict__ W2,
                __bf16* __restrict__ w1t, __bf16* __restrict__ w2t,
                float* __restrict__ uqA, float* __restrict__ uqB)
{
    int i = blockIdx.x * 256 + threadIdx.x;
    if (i < N_W1) { const int n = i >> 8, k = i & 255; w1t[i] = (__bf16)W1[k * EE + n]; return; }
    i -= N_W1;
    if (i < N_W2) { const int n = i >> 7, k = i & 127; w2t[i] = (__bf16)W2[k * EE + n]; return; }
    i -= N_W2;
    if (i < N_UQ) { uqA[i] = 0.f; return; }
    i -= N_UQ;
    if (i < N_UQ) { uqB[i] = 0.f; }
}

// ---------------------------------------------------------------------------
// Fused embed gather-sum (fp32 C, direct) + add_lm + MFMA MLP, 3 hops.
// hop 0: logits0 in-register, m0 never stored. hops 1,2: Y -> mout bf16.
// LDS: Hs/plog ALIAS Xs (Xs dead after GEMM1 K-loop; barrier-separated).
// ---------------------------------------------------------------------------
__global__ __launch_bounds__(256)
void embed_mlp_mfma(const int* __restrict__ story,
                    const int* __restrict__ kb_len,
                    const int* __restrict__ conv_len,
                    const float* __restrict__ dh,
                    const float* __restrict__ tf,
                    const float* __restrict__ C,
                    const __bf16* __restrict__ w1t, const float* __restrict__ b1,
                    const __bf16* __restrict__ w2t, const float* __restrict__ b2,
                    const float* __restrict__ gp, const float* __restrict__ query,
                    __bf16* __restrict__ mout, float* __restrict__ lbuf0)
{
    __shared__ __bf16 Xs[32 * XS_STRIDE];   // 16,896 B; Hs (8,704 B) aliases
    __shared__ int    sidx[32 * SS];
    __bf16* Hs   = Xs;                      // valid: Xs dead before H written
    float*  plog = (float*)Xs;              // valid: Hs dead before plog written

    const int bid  = blockIdx.x;
    const int hop  = bid >> 10;
    const int row0 = (bid & 1023) * 32;
    const int b    = row0 >> 11;
    const int tid  = threadIdx.x;

    const float* Ck = C + (size_t)hop * VV * EE;

    for (int i = tid; i < 32 * SS; i += 256) sidx[i] = story[(size_t)row0 * SS + i];

    const int kb   = kb_len[b];
    const int cl   = conv_len[b];
    const int rgrp = tid >> 5;              // 0..7
    const int e4   = (tid & 31) * 4;        // 4-float col group
    const float4 tf4 = *(const float4*)&tf[b * EE + e4];
    ushort4 tfp;
    tfp.x = bfbits(tf4.x); tfp.y = bfbits(tf4.y); tfp.z = bfbits(tf4.z); tfp.w = bfbits(tf4.w);
    __syncthreads();

    // ---- gather X: fp32 float4 reads, packed bf16x4 LDS stores ----
    for (int chunk = 0; chunk < 4; ++chunk) {
        const int r  = chunk * 8 + rgrp;
        const int* si = &sidx[r * SS];
        float4 v[SS];
        #pragma unroll
        for (int s = 0; s < SS; ++s)
            v[s] = *(const float4*)&Ck[(size_t)si[s] * EE + e4];
        const int j = ((row0 + r) & (MM - 1)) - kb;
        float4 acc = {0.f, 0.f, 0.f, 0.f};
        if (j >= 0 && j < cl)
            acc = *(const float4*)&dh[((size_t)b * LCC + j) * EE + e4];
        #pragma unroll
        for (int s = 0; s < SS; ++s) {
            acc.x += v[s].x; acc.y += v[s].y; acc.z += v[s].z; acc.w += v[s].w;
        }
        ushort4 pk;
        pk.x = bfbits(acc.x); pk.y = bfbits(acc.y); pk.z = bfbits(acc.z); pk.w = bfbits(acc.w);
        *(ushort4*)&Xs[r * XS_STRIDE + e4]      = pk;
        *(ushort4*)&Xs[r * XS_STRIDE + EE + e4] = tfp;
    }
    __syncthreads();

    const int w       = tid >> 6;
    const int lane    = tid & 63;
    const int lr      = lane & 15;
    const int lk      = lane >> 4;
    const int colbase = w * 32;

    // ---- GEMM1: H = lrelu(X @ W1 + b1) ----
    f32x4 acc1[2][2];
    #pragma unroll
    for (int i = 0; i < 2; ++i)
        #pragma unroll
        for (int j = 0; j < 2; ++j) acc1[i][j] = (f32x4){0.f, 0.f, 0.f, 0.f};

    for (int ks = 0; ks < 8; ++ks) {
        bf16x8 a[2], bw[2];
        #pragma unroll
        for (int mt = 0; mt < 2; ++mt)
            a[mt] = *(const bf16x8*)&Xs[(mt * 16 + lr) * XS_STRIDE + ks * 32 + lk * 8];
        #pragma unroll
        for (int nt = 0; nt < 2; ++nt)
            bw[nt] = *(const bf16x8*)&w1t[(size_t)(colbase + nt * 16 + lr) * 256 + ks * 32 + lk * 8];
        #pragma unroll
        for (int mt = 0; mt < 2; ++mt)
            #pragma unroll
            for (int nt = 0; nt < 2; ++nt)
                acc1[mt][nt] = __builtin_amdgcn_mfma_f32_16x16x32_bf16(a[mt], bw[nt], acc1[mt][nt], 0, 0, 0);
    }
    __syncthreads();   // all Xs reads complete before Hs (alias) is written
    {
        const float b1v[2] = { b1[colbase + lr], b1[colbase + 16 + lr] };
        #pragma unroll
        for (int mt = 0; mt < 2; ++mt)
            #pragma unroll
            for (int nt = 0; nt < 2; ++nt)
                #pragma unroll
                for (int reg = 0; reg < 4; ++reg) {
                    float h = acc1[mt][nt][reg] + b1v[nt];
                    h = (h > 0.f) ? h : 0.1f * h;
                    Hs[(mt * 16 + lk * 4 + reg) * HS_STRIDE + colbase + nt * 16 + lr] = (__bf16)h;
                }
    }
    __syncthreads();

    // ---- GEMM2: Y = H @ W2 + b2 ----
    f32x4 acc2[2][2];
    #pragma unroll
    for (int i = 0; i < 2; ++i)
        #pragma unroll
        for (int j = 0; j < 2; ++j) acc2[i][j] = (f32x4){0.f, 0.f, 0.f, 0.f};

    for (int ks = 0; ks < 4; ++ks) {
        bf16x8 a[2], bw[2];
        #pragma unroll
        for (int mt = 0; mt < 2; ++mt)
            a[mt] = *(const bf16x8*)&Hs[(mt * 16 + lr) * HS_STRIDE + ks * 32 + lk * 8];
        #pragma unroll
        for (int nt = 0; nt < 2; ++nt)
            bw[nt] = *(const bf16x8*)&w2t[(size_t)(colbase + nt * 16 + lr) * 128 + ks * 32 + lk * 8];
        #pragma unroll
        for (int mt = 0; mt < 2; ++mt)
            #pragma unroll
            for (int nt = 0; nt < 2; ++nt)
                acc2[mt][nt] = __builtin_amdgcn_mfma_f32_16x16x32_bf16(a[mt], bw[nt], acc2[mt][nt], 0, 0, 0);
    }

    const float b2v[2] = { b2[colbase + lr], b2[colbase + 16 + lr] };

    if (hop == 0) {
        const float qv0 = query[b * EE + colbase + lr];
        const float qv1 = query[b * EE + colbase + 16 + lr];
        __syncthreads();    // Hs reads done; reuse as plog
        #pragma unroll
        for (int mt = 0; mt < 2; ++mt)
            #pragma unroll
            for (int reg = 0; reg < 4; ++reg) {
                float p = (acc2[mt][0][reg] + b2v[0]) * qv0
                        + (acc2[mt][1][reg] + b2v[1]) * qv1;
                p += __shfl_xor(p, 1, 64);
                p += __shfl_xor(p, 2, 64);
                p += __shfl_xor(p, 4, 64);
                p += __shfl_xor(p, 8, 64);
                if (lr == 0) plog[(mt * 16 + lk * 4 + reg) * 4 + w] = p;
            }
        __syncthreads();
        if (tid < 32) {
            const float l = plog[tid * 4] + plog[tid * 4 + 1] + plog[tid * 4 + 2] + plog[tid * 4 + 3];
            lbuf0[row0 + tid] = l * gp[row0 + tid];
        }
    } else {
        __bf16* out = mout + (size_t)(hop - 1) * 32768 * EE;
        #pragma unroll
        for (int mt = 0; mt < 2; ++mt)
            #pragma unroll
            for (int nt = 0; nt < 2; ++nt)
                #pragma unroll
                for (int reg = 0; reg < 4; ++reg) {
                    const int rg_ = row0 + mt * 16 + lk * 4 + reg;
                    out[(size_t)rg_ * EE + colbase + nt * 16 + lr] =
                        (__bf16)(acc2[mt][nt][reg] + b2v[nt]);
                }
    }
}

// ---------------------------------------------------------------------------
// fused_tail: ONE cooperative kernel replacing update1/logits1/update2/
// logits2/softmax_final.  Removes 4 inter-kernel launch gaps (~10-15 µs each).
// 512 blocks x 256 threads = 2 blocks/CU -> co-residency trivially satisfied
// (LDS ~2.9 KB, modest VGPR).  Numerics identical to the split kernels.
// ---------------------------------------------------------------------------
static __device__ inline void update_phase(
    const __bf16* __restrict__ mk, const float* __restrict__ gp,
    const float* __restrict__ lbuf, float* __restrict__ uq,
    int b, int rloc0, int tid, int lane, int w,
    float* redm, float* reds, float* wls, float (*part)[128])
{
    const float* lb = lbuf + (size_t)b * MM;
    float v[8];
    float mx = -1e30f;
    #pragma unroll
    for (int i = 0; i < 8; ++i) { v[i] = lb[i * 256 + tid]; mx = fmaxf(mx, v[i]); }
    #pragma unroll
    for (int off = 32; off > 0; off >>= 1) mx = fmaxf(mx, __shfl_xor(mx, off, 64));
    if (lane == 0) redm[w] = mx;
    __syncthreads();
    mx = fmaxf(fmaxf(redm[0], redm[1]), fmaxf(redm[2], redm[3]));
    float sum = 0.f;
    #pragma unroll
    for (int i = 0; i < 8; ++i) sum += __expf(v[i] - mx);
    #pragma unroll
    for (int off = 32; off > 0; off >>= 1) sum += __shfl_xor(sum, off, 64);
    if (lane == 0) reds[w] = sum;
    __syncthreads();
    const float inv = 1.f / (reds[0] + reds[1] + reds[2] + reds[3]);

    if (tid < 64)
        wls[tid] = gp[(size_t)b * MM + rloc0 + tid] * __expf(lb[rloc0 + tid] - mx) * inv;
    __syncthreads();

    const int rgrp = tid >> 4;
    const int e8   = (tid & 15) * 8;
    float acc[8];
    #pragma unroll
    for (int q = 0; q < 8; ++q) acc[q] = 0.f;
    #pragma unroll
    for (int p = 0; p < 4; ++p) {
        const int rl  = p * 16 + rgrp;
        const float wg = wls[rl];
        const bf16x8 vv = *(const bf16x8*)&mk[((size_t)b * MM + rloc0 + rl) * EE + e8];
        #pragma unroll
        for (int q = 0; q < 8; ++q) acc[q] += wg * (float)vv[q];
    }
    #pragma unroll
    for (int q = 0; q < 8; ++q) {
        acc[q] += __shfl_xor(acc[q], 16, 64);
        acc[q] += __shfl_xor(acc[q], 32, 64);
    }
    if (lane < 16) {
        #pragma unroll
        for (int q = 0; q < 8; ++q) part[w][e8 + q] = acc[q];
    }
    __syncthreads();
    if (tid < 128) {
        const float s = part[0][tid] + part[1][tid] + part[2][tid] + part[3][tid];
        atomicAdd(&uq[b * EE + tid], s);
    }
}

static __device__ inline void logits_phase(
    const __bf16* __restrict__ mk, const float* __restrict__ gp,
    const float* __restrict__ query, const float* __restrict__ uqa,
    const float* __restrict__ uqb, float* __restrict__ out,
    int bid, int b, int tid, int lane, int w, float* uqs)
{
    const int row0 = bid * 64;
    if (tid < 128)
        uqs[tid] = query[b * EE + tid] + uqa[b * EE + tid]
                 + (uqb ? uqb[b * EE + tid] : 0.f);
    __syncthreads();
    const int g = lane >> 4, l16 = lane & 15;
    float u[8];
    #pragma unroll
    for (int j = 0; j < 8; ++j) u[j] = uqs[l16 * 8 + j];
    #pragma unroll
    for (int it = 0; it < 4; ++it) {
        const int row = row0 + it * 16 + w * 4 + g;
        const bf16x8 v = *(const bf16x8*)&mk[(size_t)row * EE + l16 * 8];
        float p = 0.f;
        #pragma unroll
        for (int j = 0; j < 8; ++j) p += (float)v[j] * u[j];
        p += __shfl_xor(p, 1, 64);
        p += __shfl_xor(p, 2, 64);
        p += __shfl_xor(p, 4, 64);
        p += __shfl_xor(p, 8, 64);
        if (l16 == 0) out[row] = p * gp[row];
    }
    __syncthreads();
}

__global__ __launch_bounds__(256)
void fused_tail(const __bf16* __restrict__ mall, const float* __restrict__ gp,
                const float* __restrict__ query, float* __restrict__ lbuf,
                float* __restrict__ uqA, float* __restrict__ uqB,
                float* __restrict__ out_logits, float* __restrict__ out_soft)
{
    cg::grid_group grid = cg::this_grid();
    __shared__ float redm[4], reds[4];
    __shared__ float wls[64];
    __shared__ float part[4][128];
    __shared__ float uqs[128];

    const int bid   = blockIdx.x;          // 0..511
    const int b     = bid >> 5;
    const int rloc0 = (bid & 31) * 64;
    const int tid   = threadIdx.x;
    const int lane  = tid & 63;
    const int w     = tid >> 6;

    const __bf16* m1 = mall;
    const __bf16* m2 = mall + (size_t)32768 * EE;

    // hop1: uqA += m1^T (gp * softmax(lbuf0))
    update_phase(m1, gp, lbuf, uqA, b, rloc0, tid, lane, w, redm, reds, wls, part);
    __threadfence();
    grid.sync();

    // logits1 = gp * (m1 (query+uqA)) -> lbuf
    logits_phase(m1, gp, query, uqA, nullptr, lbuf, bid, b, tid, lane, w, uqs);
    __threadfence();
    grid.sync();

    // hop2: uqB += m2^T (gp * softmax(lbuf))
    update_phase(m2, gp, lbuf, uqB, b, rloc0, tid, lane, w, redm, reds, wls, part);
    __threadfence();
    grid.sync();

    // logits2 = gp * (m2 (query+uqA+uqB)) -> out_logits
    logits_phase(m2, gp, query, uqA, uqB, out_logits, bid, b, tid, lane, w, uqs);
    __threadfence();
    grid.sync();

    // final softmax: every block reduces its b's full row, writes its 64-row seg
    {
        const float* lb = out_logits + (size_t)b * MM;
        float v[8];
        float mx = -1e30f;
        #pragma unroll
        for (int i = 0; i < 8; ++i) { v[i] = lb[i * 256 + tid]; mx = fmaxf(mx, v[i]); }
        #pragma unroll
        for (int off = 32; off > 0; off >>= 1) mx = fmaxf(mx, __shfl_xor(mx, off, 64));
        if (lane == 0) redm[w] = mx;
        __syncthreads();
        mx = fmaxf(fmaxf(redm[0], redm[1]), fmaxf(redm[2], redm[3]));
        float sum = 0.f;
        #pragma unroll
        for (int i = 0; i < 8; ++i) sum += __expf(v[i] - mx);
        #pragma unroll
        for (int off = 32; off > 0; off >>= 1) sum += __shfl_xor(sum, off, 64);
        if (lane == 0) reds[w] = sum;
        __syncthreads();
        const float inv = 1.f / (reds[0] + reds[1] + reds[2] + reds[3]);
        if (tid < 64)
            out_soft[(size_t)b * MM + rloc0 + tid] =
                __expf(lb[rloc0 + tid] - mx) * inv;
    }
}

// ---------------------------------------------------------------------------
extern "C" void kernel_launch(void* const* d_in, const int* in_sizes, int n_in,
                              void* d_out, int out_size, void* d_ws, size_t ws_size,
                              hipStream_t stream) {
    const int*   story    = (const int*)d_in[0];
    const int*   kb_len   = (const int*)d_in[1];
    const int*   conv_len = (const int*)d_in[2];
    // d_in[3] = hidden (dead w.r.t. outputs)
    const float* dh       = (const float*)d_in[4];
    const float* tf       = (const float*)d_in[5];
    const float* query    = (const float*)d_in[6];
    const float* gp       = (const float*)d_in[7];
    const float* C        = (const float*)d_in[8];
    const float* wA1      = (const float*)d_in[9];
    const float* bA1      = (const float*)d_in[10];
    const float* wA2      = (const float*)d_in[11];
    const float* bA2      = (const float*)d_in[12];
    // wC1/bC1/wC2/bC2, wf/bf: dead w.r.t. outputs

    char* ws = (char*)d_ws;
    const size_t M_ELEMS = (size_t)32768 * EE;
    size_t off = 0;
    __bf16* m   = (__bf16*)(ws + off); off += 2 * M_ELEMS * sizeof(__bf16);    // m1, m2
    __bf16* w1t = (__bf16*)(ws + off); off += 256 * 128 * sizeof(__bf16);
    __bf16* w2t = (__bf16*)(ws + off); off += 128 * 128 * sizeof(__bf16);
    float* lbuf = (float*)(ws + off);  off += (size_t)BB * MM * sizeof(float);
    float* uqA  = (float*)(ws + off);  off += (size_t)BB * EE * sizeof(float);
    float* uqB  = (float*)(ws + off);  off += (size_t)BB * EE * sizeof(float);

    float* out_soft   = (float*)d_out;
    float* out_logits = out_soft + (size_t)BB * MM;

    prep_small<<<N_PREP / 256, 256, 0, stream>>>(wA1, wA2, w1t, w2t, uqA, uqB);
    embed_mlp_mfma<<<3072, 256, 0, stream>>>(story, kb_len, conv_len, dh, tf, C,
                                             w1t, bA1, w2t, bA2, gp, query, m, lbuf);

    const __bf16* marg = m;
    const float*  gparg = gp;
    const float*  qarg  = query;
    float* lbarg = lbuf;
    float* uaarg = uqA;
    float* ubarg = uqB;
    float* olarg = out_logits;
    float* osarg = out_soft;
    void* args[] = { (void*)&marg, (void*)&gparg, (void*)&qarg, (void*)&lbarg,
                     (void*)&uaarg, (void*)&ubarg, (void*)&olarg, (void*)&osarg };
    hipLaunchCooperativeKernel(fused_tail, dim3(512), dim3(256), args, 0u, stream);
}